// Round 1
// baseline (144.027 us; speedup 1.0000x reference)
//
#include <hip/hip_runtime.h>
#include <math.h>

// Problem constants
#define NB   256    // batch
#define KIN  1024   // in_dim
#define ND   512    // feature dim D
#define NP   2048   // proxies / classes P

// ws layout (floats)
#define WS_FEAT   0                      // [256*512]
#define WS_LOGITS (WS_FEAT + NB*ND)      // [256*2048]
#define WS_PN2    (WS_LOGITS + NB*NP)    // [2048]
#define WS_ACC    (WS_PN2 + NP)          // [2] : sum_logp, sum_norm

// ---------------------------------------------------------------------------
// Generic NT fp32 GEMM core: C[m,n] += sum_k A[m,k]*B[n,k]
// 64x64 block tile, BK=32, 256 threads, 4x4 micro-tile with strided ownership:
//   m = m0 + ty + 16*i, n = n0 + tx + 16*j   (ty=tid>>4, tx=tid&15)
// LDS pad +4 floats keeps 16B alignment; strided ownership keeps b128 reads
// at <=2-way bank aliasing (free).
// ---------------------------------------------------------------------------
__device__ __forceinline__ void gemm_core(
    const float* __restrict__ A, const float* __restrict__ B,
    int K, int m0, int n0, int kbeg, int kend,
    float (&acc)[4][4], float (*As)[36], float (*Bs)[36])
{
    const int tid = threadIdx.x;
    const int tx = tid & 15, ty = tid >> 4;
    for (int k0 = kbeg; k0 < kend; k0 += 32) {
#pragma unroll
        for (int u = 0; u < 2; ++u) {
            int idx = tid + u * 256;           // 0..511
            int row = idx >> 3;                // 0..63
            int c4  = (idx & 7) << 2;          // 0..28
            *(float4*)&As[row][c4] = *(const float4*)&A[(size_t)(m0 + row) * K + k0 + c4];
            *(float4*)&Bs[row][c4] = *(const float4*)&B[(size_t)(n0 + row) * K + k0 + c4];
        }
        __syncthreads();
#pragma unroll
        for (int kk = 0; kk < 32; kk += 4) {
            float4 a4[4], b4[4];
#pragma unroll
            for (int i = 0; i < 4; ++i) a4[i] = *(const float4*)&As[ty + 16 * i][kk];
#pragma unroll
            for (int j = 0; j < 4; ++j) b4[j] = *(const float4*)&Bs[tx + 16 * j][kk];
#pragma unroll
            for (int i = 0; i < 4; ++i)
#pragma unroll
                for (int j = 0; j < 4; ++j) {
                    acc[i][j] += a4[i].x * b4[j].x + a4[i].y * b4[j].y
                               + a4[i].z * b4[j].z + a4[i].w * b4[j].w;
                }
        }
        __syncthreads();
    }
}

// GEMM1 (split-K=4): feat = x @ Wb.T + bb, atomic accumulate into zeroed feat
__global__ __launch_bounds__(256) void k_feat(
    const float* __restrict__ x, const float* __restrict__ Wb,
    const float* __restrict__ bb, float* __restrict__ feat)
{
    __shared__ float As[64][36];
    __shared__ float Bs[64][36];
    const int n0 = blockIdx.x * 64;   // N=512 -> gridDim.x=8
    const int m0 = blockIdx.y * 64;   // M=256 -> gridDim.y=4
    const int kz = blockIdx.z;        // 4 splits of 256
    float acc[4][4] = {};
    gemm_core(x, Wb, KIN, m0, n0, kz * 256, kz * 256 + 256, acc, As, Bs);
    const int tx = threadIdx.x & 15, ty = threadIdx.x >> 4;
#pragma unroll
    for (int i = 0; i < 4; ++i) {
        int m = m0 + ty + 16 * i;
#pragma unroll
        for (int j = 0; j < 4; ++j) {
            int n = n0 + tx + 16 * j;
            float v = acc[i][j];
            if (kz == 0) v += bb[n];
            atomicAdd(&feat[m * ND + n], v);
        }
    }
}

// GEMM2 fused: for n<2048 -> out = feat@Wm.T + bm (to d_out)
//              for n>=2048 -> logits = 2*feat@proxies.T - pn2 (to ws)
__global__ __launch_bounds__(256) void k_head(
    const float* __restrict__ feat, const float* __restrict__ Wm,
    const float* __restrict__ bm, const float* __restrict__ proxies,
    const float* __restrict__ pn2, float* __restrict__ out,
    float* __restrict__ logits)
{
    __shared__ float As[64][36];
    __shared__ float Bs[64][36];
    const int n0g = blockIdx.x * 64;  // 0..4095, gridDim.x=64
    const int m0  = blockIdx.y * 64;  // gridDim.y=4
    const bool isProxy = (n0g >= NP);
    const float* Bp = isProxy ? proxies : Wm;
    const int n0 = isProxy ? (n0g - NP) : n0g;
    float acc[4][4] = {};
    gemm_core(feat, Bp, ND, m0, n0, 0, ND, acc, As, Bs);
    const int tx = threadIdx.x & 15, ty = threadIdx.x >> 4;
#pragma unroll
    for (int i = 0; i < 4; ++i) {
        int m = m0 + ty + 16 * i;
#pragma unroll
        for (int j = 0; j < 4; ++j) {
            int n = n0 + tx + 16 * j;
            if (!isProxy) {
                out[m * NP + n] = acc[i][j] + bm[n];
            } else {
                logits[m * NP + n] = 2.0f * acc[i][j] - pn2[n];
            }
        }
    }
}

// pn2[p] = ||proxy_p||^2 ; one wave per row
__global__ __launch_bounds__(256) void k_pn2(
    const float* __restrict__ proxies, float* __restrict__ pn2)
{
    const int wave = threadIdx.x >> 6, lane = threadIdx.x & 63;
    const int row = blockIdx.x * 4 + wave;   // grid 512
    const float* pr = proxies + (size_t)row * ND;
    float s = 0.f;
#pragma unroll
    for (int c = lane; c < ND; c += 64) { float v = pr[c]; s += v * v; }
#pragma unroll
    for (int off = 32; off; off >>= 1) s += __shfl_down(s, off);
    if (lane == 0) pn2[row] = s;
}

__device__ __forceinline__ float block_reduce(float v, float* sred, int op)
{
    const int lane = threadIdx.x & 63, wave = threadIdx.x >> 6;
#pragma unroll
    for (int off = 32; off; off >>= 1) {
        float o = __shfl_down(v, off);
        v = op ? fmaxf(v, o) : (v + o);
    }
    if (lane == 0) sred[wave] = v;
    __syncthreads();
    if (threadIdx.x == 0) {
        float r = sred[0];
#pragma unroll
        for (int w = 1; w < 4; ++w) r = op ? fmaxf(r, sred[w]) : (r + sred[w]);
        sred[0] = r;
    }
    __syncthreads();
    float r = sred[0];
    __syncthreads();
    return r;
}

// per-row: logsumexp over 2048 logits + gather y + row L2 norm of feat
__global__ __launch_bounds__(256) void k_loss(
    const float* __restrict__ feat, const float* __restrict__ logits,
    const int* __restrict__ y, float* __restrict__ accum)
{
    __shared__ float sred[4];
    const int b = blockIdx.x;        // grid 256
    const int tid = threadIdx.x;

    float s = 0.f;
#pragma unroll
    for (int c = tid; c < ND; c += 256) { float v = feat[b * ND + c]; s += v * v; }
    float fn2 = block_reduce(s, sred, 0);

    const float* lr = logits + (size_t)b * NP;
    float lv[8], mx = -INFINITY;
#pragma unroll
    for (int j = 0; j < 8; ++j) { lv[j] = lr[tid + 256 * j]; mx = fmaxf(mx, lv[j]); }
    float MX = block_reduce(mx, sred, 1);
    float es = 0.f;
#pragma unroll
    for (int j = 0; j < 8; ++j) es += expf(lv[j] - MX);
    float SUM = block_reduce(es, sred, 0);

    if (tid == 0) {
        float ly = lr[y[b]];
        float logp = ly - MX - logf(SUM);
        atomicAdd(&accum[0], logp);
        atomicAdd(&accum[1], sqrtf(fn2));
    }
}

__global__ void k_final(const float* __restrict__ accum, float* __restrict__ tail)
{
    if (threadIdx.x == 0 && blockIdx.x == 0) {
        tail[0] = -accum[0] / (float)NB;   // loss
        tail[1] =  accum[1] / (float)NB;   // reg_e
    }
}

extern "C" void kernel_launch(void* const* d_in, const int* in_sizes, int n_in,
                              void* d_out, int out_size, void* d_ws, size_t ws_size,
                              hipStream_t stream)
{
    const float* x       = (const float*)d_in[0];
    const int*   y       = (const int*)  d_in[1];
    const float* Wb      = (const float*)d_in[2];
    const float* bb      = (const float*)d_in[3];
    const float* Wm      = (const float*)d_in[4];
    const float* bm      = (const float*)d_in[5];
    const float* proxies = (const float*)d_in[6];

    float* ws     = (float*)d_ws;
    float* feat   = ws + WS_FEAT;
    float* logits = ws + WS_LOGITS;
    float* pn2    = ws + WS_PN2;
    float* accum  = ws + WS_ACC;

    float* out  = (float*)d_out;            // [256*2048]
    float* tail = out + NB * NP;            // [loss, reg_e]

    // zero the atomic-accumulated regions (ws is re-poisoned each call)
    hipMemsetAsync(feat, 0, NB * ND * sizeof(float), stream);
    hipMemsetAsync(accum, 0, 2 * sizeof(float), stream);

    k_pn2 <<<dim3(NP / 4), dim3(256), 0, stream>>>(proxies, pn2);
    k_feat<<<dim3(ND / 64, NB / 64, 4), dim3(256), 0, stream>>>(x, Wb, bb, feat);
    k_head<<<dim3((NP * 2) / 64, NB / 64), dim3(256), 0, stream>>>(
        feat, Wm, bm, proxies, pn2, out, logits);
    k_loss<<<dim3(NB), dim3(256), 0, stream>>>(feat, logits, y, accum);
    k_final<<<dim3(1), dim3(64), 0, stream>>>(accum, tail);
}

// Round 2
// 99.788 us; speedup vs baseline: 1.4433x; 1.4433x over previous
//
#include <hip/hip_runtime.h>
#include <math.h>

// Problem constants
#define NB   256
#define KIN  1024
#define ND   512
#define NP   2048
#define NTOT 4096   // Wm rows (2048) + proxy rows (2048) stacked

typedef __bf16 bf16x8 __attribute__((ext_vector_type(8)));
typedef float  f32x4  __attribute__((ext_vector_type(4)));
typedef unsigned short ush8 __attribute__((ext_vector_type(8)));

// ws byte offsets (all 16B aligned)
#define OFF_XB     0u          // 256*1024 bf16  = 512 KB
#define OFF_WBB    524288u     // 512*1024 bf16  = 1 MB
#define OFF_WPB    1572864u    // 4096*512 bf16  = 4 MB
#define OFF_FEATB  5767168u    // 256*512 bf16   = 256 KB
#define OFF_PN2    6029312u    // 2048 f32
#define OFF_LOGITS 6037504u    // 256*2048 f32   = 2 MB
#define OFF_ROWLP  8134656u    // 256 f32
#define OFF_ROWNM  8135680u    // 256 f32

__device__ __forceinline__ unsigned short f2bf(float f) {
    union { float f; unsigned u; } v; v.f = f;
    unsigned r = v.u + 0x7fffu + ((v.u >> 16) & 1u);   // RNE
    return (unsigned short)(r >> 16);
}
__device__ __forceinline__ float bf2f(unsigned short h) {
    union { unsigned u; float f; } v; v.u = ((unsigned)h) << 16; return v.f;
}

// ---------------------------------------------------------------------------
// MFMA GEMM core: C[m,n] = sum_k A[m,k]*B[n,k], A,B bf16 row-major [rows][K].
// 64x64 block tile, BK=32, 256 thr = 4 waves in 2x2; wave tile 32x32 as
// 2x2 MFMAs of 16x16x32. Verified layouts (m89/m91): A[m=lane&15][k=quad*8+j],
// C/D: n=lane&15, m=quad*4+reg.
// ---------------------------------------------------------------------------
template <int KDIM, int KSTEPS>
__device__ __forceinline__ void mfma_core(
    const unsigned short* __restrict__ A, const unsigned short* __restrict__ B,
    int m0, int n0, unsigned short* As, unsigned short* Bs, f32x4 (&acc)[2][2])
{
    const int t = threadIdx.x;
    const int lane = t & 63, w = t >> 6;
    const int wm = (w >> 1) * 32, wn = (w & 1) * 32;
    // staging: thread t loads 8 bf16 of row (t>>2), k-chunk (t&3)*8
    const int srow = t >> 2, sc = (t & 3) * 8;
    const unsigned short* ga = A + (size_t)(m0 + srow) * KDIM + sc;
    const unsigned short* gb = B + (size_t)(n0 + srow) * KDIM + sc;
    const int arow = wm + (lane & 15), brow = wn + (lane & 15);
    const int fcol = (lane >> 4) * 8;

    for (int ks = 0; ks < KSTEPS; ++ks) {
        ush8 va = *(const ush8*)(ga + ks * 32);
        ush8 vb = *(const ush8*)(gb + ks * 32);
        __syncthreads();                    // all waves done reading prev tile
        *(ush8*)&As[srow * 32 + sc] = va;
        *(ush8*)&Bs[srow * 32 + sc] = vb;
        __syncthreads();
        bf16x8 af0 = *(const bf16x8*)&As[(arow     ) * 32 + fcol];
        bf16x8 af1 = *(const bf16x8*)&As[(arow + 16) * 32 + fcol];
        bf16x8 bf0 = *(const bf16x8*)&Bs[(brow     ) * 32 + fcol];
        bf16x8 bf1 = *(const bf16x8*)&Bs[(brow + 16) * 32 + fcol];
        acc[0][0] = __builtin_amdgcn_mfma_f32_16x16x32_bf16(af0, bf0, acc[0][0], 0, 0, 0);
        acc[0][1] = __builtin_amdgcn_mfma_f32_16x16x32_bf16(af0, bf1, acc[0][1], 0, 0, 0);
        acc[1][0] = __builtin_amdgcn_mfma_f32_16x16x32_bf16(af1, bf0, acc[1][0], 0, 0, 0);
        acc[1][1] = __builtin_amdgcn_mfma_f32_16x16x32_bf16(af1, bf1, acc[1][1], 0, 0, 0);
    }
}

// prep: cast x/Wb/Wm/proxies -> bf16 (Wm+proxies stacked), compute pn2
__global__ __launch_bounds__(256) void k_prep(
    const float* __restrict__ x, const float* __restrict__ Wb,
    const float* __restrict__ Wm, const float* __restrict__ prox,
    unsigned short* __restrict__ xb, unsigned short* __restrict__ Wbb,
    unsigned short* __restrict__ WPb, float* __restrict__ pn2)
{
    const int bid = blockIdx.x, t = threadIdx.x;
    const float* src; unsigned short* dst; int b;
    if (bid < 128)       { src = x;    dst = xb;  b = bid; }
    else if (bid < 384)  { src = Wb;   dst = Wbb; b = bid - 128; }
    else if (bid < 896)  { src = Wm;   dst = WPb; b = bid - 384; }
    else if (bid < 1408) { src = prox; dst = WPb + (size_t)NP * ND; b = bid - 896; }
    else {
        // pn2: 512 blocks x 4 waves = 2048 rows
        const int wave = t >> 6, lane = t & 63;
        const int row = (bid - 1408) * 4 + wave;
        const float* pr = prox + (size_t)row * ND + lane * 8;
        float4 v0 = *(const float4*)pr;
        float4 v1 = *(const float4*)(pr + 4);
        float s = v0.x*v0.x + v0.y*v0.y + v0.z*v0.z + v0.w*v0.w
                + v1.x*v1.x + v1.y*v1.y + v1.z*v1.z + v1.w*v1.w;
#pragma unroll
        for (int off = 32; off; off >>= 1) s += __shfl_down(s, off);
        if (lane == 0) pn2[row] = s;
        return;
    }
    const int idx = (b * 256 + t) * 8;
    float4 f0 = *(const float4*)(src + idx);
    float4 f1 = *(const float4*)(src + idx + 4);
    ush8 o;
    o[0] = f2bf(f0.x); o[1] = f2bf(f0.y); o[2] = f2bf(f0.z); o[3] = f2bf(f0.w);
    o[4] = f2bf(f1.x); o[5] = f2bf(f1.y); o[6] = f2bf(f1.z); o[7] = f2bf(f1.w);
    *(ush8*)(dst + idx) = o;
}

// GEMM1: featb = bf16(x @ Wb.T + bb)
__global__ __launch_bounds__(256) void k_feat(
    const unsigned short* __restrict__ xb, const unsigned short* __restrict__ Wbb,
    const float* __restrict__ bb, unsigned short* __restrict__ featb)
{
    __shared__ unsigned short As[64 * 32];
    __shared__ unsigned short Bs[64 * 32];
    const int n0 = blockIdx.x * 64;   // 8
    const int m0 = blockIdx.y * 64;   // 4
    f32x4 acc[2][2] = {};
    mfma_core<KIN, KIN / 32>(xb, Wbb, m0, n0, As, Bs, acc);
    const int lane = threadIdx.x & 63, w = threadIdx.x >> 6;
    const int wm = (w >> 1) * 32, wn = (w & 1) * 32;
    const int q = lane >> 4, cn = lane & 15;
#pragma unroll
    for (int i = 0; i < 2; ++i)
#pragma unroll
        for (int j = 0; j < 2; ++j) {
            const int n = n0 + wn + 16 * j + cn;
            const float bias = bb[n];
#pragma unroll
            for (int r = 0; r < 4; ++r) {
                const int m = m0 + wm + 16 * i + q * 4 + r;
                featb[m * ND + n] = f2bf(acc[i][j][r] + bias);
            }
        }
}

// GEMM2 fused: n<2048 -> out = feat@Wm.T + bm ; n>=2048 -> logits = 2*dot - pn2
__global__ __launch_bounds__(256) void k_head(
    const unsigned short* __restrict__ featb, const unsigned short* __restrict__ WPb,
    const float* __restrict__ bm, const float* __restrict__ pn2,
    float* __restrict__ out, float* __restrict__ logits)
{
    __shared__ unsigned short As[64 * 32];
    __shared__ unsigned short Bs[64 * 32];
    const int n0 = blockIdx.x * 64;   // 64 blocks over N=4096
    const int m0 = blockIdx.y * 64;   // 4
    f32x4 acc[2][2] = {};
    mfma_core<ND, ND / 32>(featb, WPb, m0, n0, As, Bs, acc);
    const int lane = threadIdx.x & 63, w = threadIdx.x >> 6;
    const int wm = (w >> 1) * 32, wn = (w & 1) * 32;
    const int q = lane >> 4, cn = lane & 15;
    const bool isProxy = (n0 >= NP);
#pragma unroll
    for (int i = 0; i < 2; ++i)
#pragma unroll
        for (int j = 0; j < 2; ++j) {
            const int n = n0 + wn + 16 * j + cn;
            const float cadd = isProxy ? pn2[n - NP] : bm[n];
#pragma unroll
            for (int r = 0; r < 4; ++r) {
                const int m = m0 + wm + 16 * i + q * 4 + r;
                const float v = acc[i][j][r];
                if (isProxy) logits[m * NP + (n - NP)] = 2.0f * v - cadd;
                else         out[m * NP + n] = v + cadd;
            }
        }
}

__device__ __forceinline__ float block_reduce(float v, float* sred, int op)
{
    const int lane = threadIdx.x & 63, wave = threadIdx.x >> 6;
#pragma unroll
    for (int off = 32; off; off >>= 1) {
        float o = __shfl_down(v, off);
        v = op ? fmaxf(v, o) : (v + o);
    }
    if (lane == 0) sred[wave] = v;
    __syncthreads();
    if (threadIdx.x == 0) {
        float r = sred[0];
#pragma unroll
        for (int wv = 1; wv < 4; ++wv) r = op ? fmaxf(r, sred[wv]) : (r + sred[wv]);
        sred[0] = r;
    }
    __syncthreads();
    float r = sred[0];
    __syncthreads();
    return r;
}

// per-row: logsumexp + gather + feat row norm -> rowlp/rownm
__global__ __launch_bounds__(256) void k_loss(
    const unsigned short* __restrict__ featb, const float* __restrict__ logits,
    const int* __restrict__ y, float* __restrict__ rowlp, float* __restrict__ rownm)
{
    __shared__ float sred[4];
    const int b = blockIdx.x, t = threadIdx.x;

    float s = 0.f;
#pragma unroll
    for (int c = 0; c < 2; ++c) {
        float v = bf2f(featb[b * ND + t * 2 + c]); s += v * v;
    }
    float fn2 = block_reduce(s, sred, 0);

    const float* lr = logits + (size_t)b * NP;
    float lv[8], mx = -INFINITY;
#pragma unroll
    for (int j = 0; j < 8; ++j) { lv[j] = lr[t + 256 * j]; mx = fmaxf(mx, lv[j]); }
    float MX = block_reduce(mx, sred, 1);
    float es = 0.f;
#pragma unroll
    for (int j = 0; j < 8; ++j) es += __expf(lv[j] - MX);
    float SUM = block_reduce(es, sred, 0);

    if (t == 0) {
        float ly = lr[y[b]];
        rowlp[b] = ly - MX - __logf(SUM);
        rownm[b] = sqrtf(fn2);
    }
}

__global__ __launch_bounds__(256) void k_final(
    const float* __restrict__ rowlp, const float* __restrict__ rownm,
    float* __restrict__ tail)
{
    __shared__ float sred[4];
    const int t = threadIdx.x;
    float s1 = block_reduce(rowlp[t], sred, 0);
    float s2 = block_reduce(rownm[t], sred, 0);
    if (t == 0) {
        tail[0] = -s1 / (float)NB;
        tail[1] =  s2 / (float)NB;
    }
}

extern "C" void kernel_launch(void* const* d_in, const int* in_sizes, int n_in,
                              void* d_out, int out_size, void* d_ws, size_t ws_size,
                              hipStream_t stream)
{
    const float* x       = (const float*)d_in[0];
    const int*   y       = (const int*)  d_in[1];
    const float* Wb      = (const float*)d_in[2];
    const float* bb      = (const float*)d_in[3];
    const float* Wm      = (const float*)d_in[4];
    const float* bm      = (const float*)d_in[5];
    const float* proxies = (const float*)d_in[6];

    char* ws = (char*)d_ws;
    unsigned short* xb     = (unsigned short*)(ws + OFF_XB);
    unsigned short* Wbb    = (unsigned short*)(ws + OFF_WBB);
    unsigned short* WPb    = (unsigned short*)(ws + OFF_WPB);
    unsigned short* featb  = (unsigned short*)(ws + OFF_FEATB);
    float*          pn2    = (float*)(ws + OFF_PN2);
    float*          logits = (float*)(ws + OFF_LOGITS);
    float*          rowlp  = (float*)(ws + OFF_ROWLP);
    float*          rownm  = (float*)(ws + OFF_ROWNM);

    float* out  = (float*)d_out;
    float* tail = out + (size_t)NB * NP;

    k_prep<<<dim3(1920), dim3(256), 0, stream>>>(x, Wb, Wm, proxies, xb, Wbb, WPb, pn2);
    k_feat<<<dim3(ND / 64, NB / 64), dim3(256), 0, stream>>>(xb, Wbb, bb, featb);
    k_head<<<dim3(NTOT / 64, NB / 64), dim3(256), 0, stream>>>(featb, WPb, bm, pn2, out, logits);
    k_loss<<<dim3(NB), dim3(256), 0, stream>>>(featb, logits, y, rowlp, rownm);
    k_final<<<dim3(1), dim3(256), 0, stream>>>(rowlp, rownm, tail);
}